// Round 1
// baseline (466.586 us; speedup 1.0000x reference)
//
#include <hip/hip_runtime.h>
#include <math.h>

// CARAFE upsample: B=8, C=128, H=W=64, S=2, K=5, M=64, n_enc=100
// Pipeline: K1 compress (1x1 conv) -> ws.m
//           K2 encoder (3x3 conv) + bias + pixelshuffle + softmax -> ws.wgt
//           K3 reassembly (25-tap weighted local sum, nearest-upsampled) -> out
//
// ws layout: m   = ws[0 .. 2097152)              (8 MiB,  [b][mo][h][w])
//            wgt = ws[2097152 .. 5373952)        (13.1 MiB, [b][kk][oh][ow])

#define BB 8
#define CC 128
#define HH 64
#define WW 64
#define MM 64
#define NENC 100

// ---------------------------------------------------------------------------
// K1: m[b][mo][h][w] = sum_c x[b][c][h][w] * cw[mo][c] + cb[mo]
// Block per (b, h-row): 512 blocks x 256 threads. 4x4 register tile (mo x px).
// ---------------------------------------------------------------------------
__global__ __launch_bounds__(256) void k_compress(
    const float* __restrict__ x, const float* __restrict__ cw,
    const float* __restrict__ cb, float* __restrict__ m) {
  __shared__ __align__(16) float cw_s[64][129];  // pad->129 kills 4-way bank conflict
  __shared__ __align__(16) float x_s[64][64];
  const int b = blockIdx.x >> 6;
  const int h = blockIdx.x & 63;
  const int t = threadIdx.x;

  for (int idx = t; idx < 64 * 128; idx += 256) {
    int mo = idx >> 7, c = idx & 127;
    cw_s[mo][c] = cw[mo * 128 + c];
  }

  const int px_g = t & 15;   // 16 pixel groups of 4
  const int mo_g = t >> 4;   // 16 mo groups of 4
  const int mo0 = mo_g * 4;
  const int px0 = px_g * 4;

  float acc[4][4];
#pragma unroll
  for (int i = 0; i < 4; ++i)
#pragma unroll
    for (int j = 0; j < 4; ++j) acc[i][j] = 0.f;

  for (int c0 = 0; c0 < 128; c0 += 64) {
    __syncthreads();
    for (int idx = t; idx < 64 * 64; idx += 256) {
      int c = idx >> 6, px = idx & 63;
      x_s[c][px] = x[((b * 128 + c0 + c) * 64 + h) * 64 + px];
    }
    __syncthreads();
    for (int c = 0; c < 64; ++c) {
      float4 xv = *(const float4*)&x_s[c][px0];
      float w0 = cw_s[mo0 + 0][c0 + c];
      float w1 = cw_s[mo0 + 1][c0 + c];
      float w2 = cw_s[mo0 + 2][c0 + c];
      float w3 = cw_s[mo0 + 3][c0 + c];
      acc[0][0] += w0 * xv.x; acc[0][1] += w0 * xv.y; acc[0][2] += w0 * xv.z; acc[0][3] += w0 * xv.w;
      acc[1][0] += w1 * xv.x; acc[1][1] += w1 * xv.y; acc[1][2] += w1 * xv.z; acc[1][3] += w1 * xv.w;
      acc[2][0] += w2 * xv.x; acc[2][1] += w2 * xv.y; acc[2][2] += w2 * xv.z; acc[2][3] += w2 * xv.w;
      acc[3][0] += w3 * xv.x; acc[3][1] += w3 * xv.y; acc[3][2] += w3 * xv.z; acc[3][3] += w3 * xv.w;
    }
  }

#pragma unroll
  for (int i = 0; i < 4; ++i) {
    float bias = cb[mo0 + i];
    float4 v = make_float4(acc[i][0] + bias, acc[i][1] + bias,
                           acc[i][2] + bias, acc[i][3] + bias);
    *(float4*)&m[((b * 64 + mo0 + i) * 64 + h) * 64 + px0] = v;
  }
}

// ---------------------------------------------------------------------------
// K2: encoder 3x3 SAME conv (64->100 ch) + bias + pixelshuffle + softmax(25).
// Block per (b, h): 512 blocks x 256 threads (4 waves).
// Wave `wv` owns encoder channels n in [wv*25, wv*25+25), lane = w.
// mo chunked by 4: 36 m values live in registers, reused across 25 channels;
// encoder weights via wave-uniform (scalar) loads.
// LDS m_s reused as raw[100][64] for the softmax transpose.
// wgt layout written: wgt[b][kk][oh][ow], oh=2h+(q>>1), ow=2w+(q&1), q=n%4, kk=n/4.
// ---------------------------------------------------------------------------
__global__ __launch_bounds__(256) void k_encoder_softmax(
    const float* __restrict__ m, const float* __restrict__ ew,
    const float* __restrict__ eb, float* __restrict__ wgt) {
  __shared__ __align__(16) float m_s[3 * 64 * 64];  // [dh][mo][w]; reused as raw[100][64]
  const int b = blockIdx.x >> 6;
  const int h = blockIdx.x & 63;
  const int t = threadIdx.x;

  for (int idx = t; idx < 3 * 64 * 64; idx += 256) {
    int dh = idx >> 12;
    int mo = (idx >> 6) & 63;
    int w = idx & 63;
    int hh = h + dh - 1;
    m_s[idx] = (hh >= 0 && hh < 64) ? m[((b * 64 + mo) * 64 + hh) * 64 + w] : 0.f;
  }
  __syncthreads();

  const int wave = __builtin_amdgcn_readfirstlane((int)(threadIdx.x >> 6));
  const int lane = t & 63;

  float acc[25];
#pragma unroll
  for (int i = 0; i < 25; ++i) acc[i] = 0.f;

  for (int mo0 = 0; mo0 < 64; mo0 += 4) {
    float mreg[4][3][3];
#pragma unroll
    for (int i = 0; i < 4; ++i)
#pragma unroll
      for (int dh = 0; dh < 3; ++dh)
#pragma unroll
        for (int dw = 0; dw < 3; ++dw) {
          int wv = lane + dw - 1;
          int wc = min(max(wv, 0), 63);
          float val = m_s[(dh * 64 + mo0 + i) * 64 + wc];
          mreg[i][dh][dw] = (wv >= 0 && wv < 64) ? val : 0.f;
        }
#pragma unroll
    for (int ni = 0; ni < 25; ++ni) {
      const int n = wave * 25 + ni;
      const float* __restrict__ ewp = ew + (size_t)(n * 64 + mo0) * 9;
#pragma unroll
      for (int i = 0; i < 4; ++i)
#pragma unroll
        for (int dh = 0; dh < 3; ++dh)
#pragma unroll
          for (int dw = 0; dw < 3; ++dw)
            acc[ni] += mreg[i][dh][dw] * ewp[i * 9 + dh * 3 + dw];
    }
  }

  __syncthreads();  // all reads of m_s complete
  float* raw = m_s; // reuse LDS: raw[n][w]
#pragma unroll
  for (int ni = 0; ni < 25; ++ni) {
    int n = wave * 25 + ni;
    raw[n * 64 + lane] = acc[ni] + eb[n];
  }
  __syncthreads();

  // softmax over kk for q = wave, w = lane
  const int q = wave;
  float v[25];
  float mx = -1e30f;
#pragma unroll
  for (int kk = 0; kk < 25; ++kk) {
    v[kk] = raw[(kk * 4 + q) * 64 + lane];
    mx = fmaxf(mx, v[kk]);
  }
  float sum = 0.f;
#pragma unroll
  for (int kk = 0; kk < 25; ++kk) {
    v[kk] = __expf(v[kk] - mx);
    sum += v[kk];
  }
  float inv = 1.f / sum;
  const int oh = 2 * h + (q >> 1);
  const int ow = 2 * lane + (q & 1);
#pragma unroll
  for (int kk = 0; kk < 25; ++kk)
    wgt[((b * 25 + kk) * 128 + oh) * 128 + ow] = v[kk] * inv;
}

// ---------------------------------------------------------------------------
// K3: out[b][c][oh][ow] = sum_{i,j} x[b][c][h+i-2][w+j-2] * wgt[b][i*5+j][oh][ow]
//     (h=oh/2, w=ow/2, zero-padded x). Block per (b, oh): 1024 blocks x 256 thr.
// c chunked by 32 (x halo tile in LDS); thread computes 8 c x 2 ow (the ow pair
// 2w,2w+1 shares identical x reads). float2 stores -> fully coalesced.
// ---------------------------------------------------------------------------
__global__ __launch_bounds__(256) void k_reassemble(
    const float* __restrict__ x, const float* __restrict__ wgt,
    float* __restrict__ out) {
  __shared__ __align__(16) float wgt_s[25][128];
  __shared__ __align__(16) float x_s[32][5][68];
  const int b = blockIdx.x >> 7;
  const int oh = blockIdx.x & 127;
  const int h = oh >> 1;
  const int t = threadIdx.x;

  for (int idx = t; idx < 25 * 128; idx += 256) {
    int kk = idx >> 7, ow = idx & 127;
    wgt_s[kk][ow] = wgt[((b * 25 + kk) * 128 + oh) * 128 + ow];
  }

  const int w = t & 63;
  const int g = t >> 6;  // 4 channel groups of 8

  for (int cc0 = 0; cc0 < 128; cc0 += 32) {
    __syncthreads();
    for (int idx = t; idx < 32 * 5 * 68; idx += 256) {
      int cl = idx / 340;
      int rem = idx - cl * 340;
      int r = rem / 68;
      int wi = rem - r * 68;
      int hh = h + r - 2;
      int ww = wi - 2;
      x_s[cl][r][wi] = (hh >= 0 && hh < 64 && ww >= 0 && ww < 64)
                           ? x[((b * 128 + cc0 + cl) * 64 + hh) * 64 + ww]
                           : 0.f;
    }
    __syncthreads();

    float acc0[8], acc1[8];
#pragma unroll
    for (int k = 0; k < 8; ++k) { acc0[k] = 0.f; acc1[k] = 0.f; }

#pragma unroll
    for (int i = 0; i < 5; ++i)
#pragma unroll
      for (int j = 0; j < 5; ++j) {
        const int ij = i * 5 + j;
        float w0 = wgt_s[ij][2 * w];
        float w1 = wgt_s[ij][2 * w + 1];
#pragma unroll
        for (int k = 0; k < 8; ++k) {
          float xv = x_s[g * 8 + k][i][w + j];
          acc0[k] += xv * w0;
          acc1[k] += xv * w1;
        }
      }

#pragma unroll
    for (int k = 0; k < 8; ++k) {
      int c = cc0 + g * 8 + k;
      float2 v = make_float2(acc0[k], acc1[k]);
      *(float2*)&out[(size_t)((b * 128 + c) * 128 + oh) * 128 + 2 * w] = v;
    }
  }
}

// ---------------------------------------------------------------------------
extern "C" void kernel_launch(void* const* d_in, const int* in_sizes, int n_in,
                              void* d_out, int out_size, void* d_ws, size_t ws_size,
                              hipStream_t stream) {
  (void)in_sizes; (void)n_in; (void)out_size; (void)ws_size;
  const float* x  = (const float*)d_in[0];
  const float* cw = (const float*)d_in[1];
  const float* cb = (const float*)d_in[2];
  const float* ew = (const float*)d_in[3];
  const float* eb = (const float*)d_in[4];
  float* out = (float*)d_out;
  float* ws  = (float*)d_ws;
  float* m   = ws;             // 8*64*64*64   = 2,097,152 floats
  float* wgt = ws + 2097152;   // 8*25*128*128 = 3,276,800 floats

  k_compress<<<dim3(512), dim3(256), 0, stream>>>(x, cw, cb, m);
  k_encoder_softmax<<<dim3(512), dim3(256), 0, stream>>>(m, ew, eb, wgt);
  k_reassemble<<<dim3(1024), dim3(256), 0, stream>>>(x, wgt, out);
}

// Round 2
// 194.553 us; speedup vs baseline: 2.3982x; 2.3982x over previous
//
#include <hip/hip_runtime.h>
#include <math.h>

// CARAFE upsample: B=8, C=128, H=W=64, S=2, K=5, M=64, n_enc=100 (pad 128)
// K0 prep:     ew -> a_prep[9 tap][128 n][64 mo] bf16 (zero-padded n>=100)
// K1 compress: x -> m_t[b][h][w][mo] bf16 (transposed for MFMA B-frags)
// K2 encoder:  bf16 MFMA implicit GEMM (M=128n, K=576, N=64px/block)
//              + bias + pixelshuffle + softmax -> wgt_bf[b][25][128][128] bf16
// K3 reassemble: 25-tap weighted sum, oh-pair per block.

typedef __attribute__((ext_vector_type(8))) short short8;
typedef __attribute__((ext_vector_type(4))) float floatx4;

__device__ __forceinline__ unsigned short f2bf(float f) {
  union { float f; unsigned int u; } v; v.f = f;
  unsigned int u = v.u + 0x7fffu + ((v.u >> 16) & 1u);  // RNE
  return (unsigned short)(u >> 16);
}
__device__ __forceinline__ float bf2f(unsigned short s) {
  union { unsigned int u; float f; } v; v.u = ((unsigned int)s) << 16;
  return v.f;
}

// ---------------------------------------------------------------------------
// K0: a_prep[tap][n][mo] = bf16(ew[n][mo][tap]), n>=100 -> 0.   73728 elems.
// ---------------------------------------------------------------------------
__global__ __launch_bounds__(256) void k_prep(const float* __restrict__ ew,
                                              unsigned short* __restrict__ a_prep) {
  int idx = blockIdx.x * 256 + threadIdx.x;
  if (idx >= 9 * 128 * 64) return;
  int mo = idx & 63;
  int n = (idx >> 6) & 127;
  int tap = idx >> 13;
  float v = (n < 100) ? ew[(n * 64 + mo) * 9 + tap] : 0.f;
  a_prep[idx] = f2bf(v);
}

// ---------------------------------------------------------------------------
// K1: m_t[b][h][w][mo] = bf16( sum_c x[b][c][h][w]*cw[mo][c] + cb[mo] )
// Block per (b,h): 512 blocks x 256 threads, 4x4 (mo x px) register tile.
// cw staged transposed [c][mo] (pad 68) -> float4 weight reads.
// ---------------------------------------------------------------------------
__global__ __launch_bounds__(256) void k_compress(
    const float* __restrict__ x, const float* __restrict__ cw,
    const float* __restrict__ cb, unsigned short* __restrict__ m_t) {
  __shared__ __align__(16) float cw_t[128][68];  // [c][mo], pad 68 (272B rows, 16B-aligned)
  __shared__ __align__(16) float x_s[64][64];
  const int b = blockIdx.x >> 6;
  const int h = blockIdx.x & 63;
  const int t = threadIdx.x;

  for (int idx = t; idx < 64 * 128; idx += 256) {
    int mo = idx >> 7, c = idx & 127;
    cw_t[c][mo] = cw[mo * 128 + c];
  }

  const int mo_g = t & 15;   // consecutive lanes -> consecutive mo groups (coalesced stores)
  const int px_g = t >> 4;
  const int mo0 = mo_g * 4;
  const int px0 = px_g * 4;

  float acc[4][4];
#pragma unroll
  for (int i = 0; i < 4; ++i)
#pragma unroll
    for (int j = 0; j < 4; ++j) acc[i][j] = 0.f;

  for (int c0 = 0; c0 < 128; c0 += 64) {
    __syncthreads();
    for (int idx = t; idx < 64 * 64; idx += 256) {
      int c = idx >> 6, px = idx & 63;
      x_s[c][px] = x[((b * 128 + c0 + c) * 64 + h) * 64 + px];
    }
    __syncthreads();
#pragma unroll 4
    for (int c = 0; c < 64; ++c) {
      float4 xv = *(const float4*)&x_s[c][px0];
      float4 wv = *(const float4*)&cw_t[c0 + c][mo0];
      acc[0][0] += wv.x * xv.x; acc[0][1] += wv.x * xv.y; acc[0][2] += wv.x * xv.z; acc[0][3] += wv.x * xv.w;
      acc[1][0] += wv.y * xv.x; acc[1][1] += wv.y * xv.y; acc[1][2] += wv.y * xv.z; acc[1][3] += wv.y * xv.w;
      acc[2][0] += wv.z * xv.x; acc[2][1] += wv.z * xv.y; acc[2][2] += wv.z * xv.z; acc[2][3] += wv.z * xv.w;
      acc[3][0] += wv.w * xv.x; acc[3][1] += wv.w * xv.y; acc[3][2] += wv.w * xv.z; acc[3][3] += wv.w * xv.w;
    }
  }

  float b0 = cb[mo0], b1 = cb[mo0 + 1], b2 = cb[mo0 + 2], b3 = cb[mo0 + 3];
#pragma unroll
  for (int j = 0; j < 4; ++j) {
    ushort4 mv;
    mv.x = f2bf(acc[0][j] + b0);
    mv.y = f2bf(acc[1][j] + b1);
    mv.z = f2bf(acc[2][j] + b2);
    mv.w = f2bf(acc[3][j] + b3);
    *(ushort4*)&m_t[(((b * 64 + h) * 64 + px0 + j) * 64) + mo0] = mv;
  }
}

// ---------------------------------------------------------------------------
// K2: bf16 MFMA encoder conv + bias + pixelshuffle + softmax.
// Block per (b,h): 512 blocks x 256 threads (4 waves).
// GEMM: C[128 n][64 px] = sum_{k=576} A[n][k] * B[k][px],
//   k = tap*64+mo, A from a_prep (global, L2-hot), B from m_s (LDS, im2col).
// Wave w owns n in [32w, 32w+32): 2 n-tiles x 4 px-tiles of 16x16, 8 MFMA/k-step.
// m_s rows padded 64->72 mo (144B: 16B-aligned, contiguous-b128 bank pattern).
// Epilogue: raw[128][66] LDS transpose -> softmax over 25 kk -> wgt_bf.
// ---------------------------------------------------------------------------
__global__ __launch_bounds__(256) void k_encoder_softmax(
    const unsigned short* __restrict__ m_t, const unsigned short* __restrict__ a_prep,
    const float* __restrict__ eb, unsigned short* __restrict__ wgt_bf) {
  __shared__ __align__(16) unsigned short m_s[3 * 64 * 72];  // [dh][w][mo pad 72] 27.6KB
  __shared__ __align__(16) float raw[128 * 66];              // [n][px pad 66]    33.8KB
  const int b = blockIdx.x >> 6;
  const int h = blockIdx.x & 63;
  const int t = threadIdx.x;

  // stage 3 m rows (h-1,h,h+1), 16B chunks; OOB rows -> 0
  for (int idx = t; idx < 3 * 64 * 8; idx += 256) {
    int r = idx >> 9;
    int rem = idx & 511;
    int w = rem >> 3, u = rem & 7;
    int hh = h + r - 1;
    uint4 val = make_uint4(0u, 0u, 0u, 0u);
    if (hh >= 0 && hh < 64)
      val = *(const uint4*)&m_t[(((b * 64 + hh) * 64 + w) * 64) + u * 8];
    *(uint4*)&m_s[(r * 64 + w) * 72 + u * 8] = val;
  }
  __syncthreads();

  const int wave = t >> 6, lane = t & 63;
  const int quad = lane >> 4, col = lane & 15;
  const int nbase = wave * 32;

  const floatx4 z4 = {0.f, 0.f, 0.f, 0.f};
  floatx4 acc[2][4];
#pragma unroll
  for (int i = 0; i < 2; ++i)
#pragma unroll
    for (int p = 0; p < 4; ++p) acc[i][p] = z4;

  const short8 z8 = {0, 0, 0, 0, 0, 0, 0, 0};

#pragma unroll
  for (int tap = 0; tap < 9; ++tap) {
    const int dh = tap / 3, dw = tap % 3;
#pragma unroll
    for (int half = 0; half < 2; ++half) {
      const int mo0 = half * 32;
      // A-fragments straight from global (147KB matrix, L2-resident)
      short8 a0 = *(const short8*)&a_prep[((tap * 128 + nbase + col) * 64) + mo0 + quad * 8];
      short8 a1 = *(const short8*)&a_prep[((tap * 128 + nbase + 16 + col) * 64) + mo0 + quad * 8];
#pragma unroll
      for (int p = 0; p < 4; ++p) {
        int wsrc = p * 16 + col + dw - 1;
        int wc = min(max(wsrc, 0), 63);
        short8 bf = *(const short8*)&m_s[(dh * 64 + wc) * 72 + mo0 + quad * 8];
        if (wsrc < 0 || wsrc > 63) bf = z8;  // zero-pad border column
        acc[0][p] = __builtin_amdgcn_mfma_f32_16x16x32_bf16(a0, bf, acc[0][p], 0, 0, 0);
        acc[1][p] = __builtin_amdgcn_mfma_f32_16x16x32_bf16(a1, bf, acc[1][p], 0, 0, 0);
      }
    }
  }

  // C/D layout: col = lane&15, row = quad*4 + reg  [m89-verified]
#pragma unroll
  for (int i = 0; i < 2; ++i)
#pragma unroll
    for (int p = 0; p < 4; ++p)
#pragma unroll
      for (int r = 0; r < 4; ++r)
        raw[(nbase + i * 16 + quad * 4 + r) * 66 + p * 16 + col] = acc[i][p][r];
  __syncthreads();

  // softmax over kk (n = kk*4 + q), q = wave, px = lane
  const int q = wave;
  float v[25];
  float mx = -1e30f;
#pragma unroll
  for (int kk = 0; kk < 25; ++kk) {
    v[kk] = raw[(kk * 4 + q) * 66 + lane] + eb[kk * 4 + q];
    mx = fmaxf(mx, v[kk]);
  }
  float s = 0.f;
#pragma unroll
  for (int kk = 0; kk < 25; ++kk) {
    v[kk] = __expf(v[kk] - mx);
    s += v[kk];
  }
  float inv = 1.f / s;
  const int oh = 2 * h + (q >> 1);
  const int ow2 = 2 * lane + (q & 1);
#pragma unroll
  for (int kk = 0; kk < 25; ++kk)
    wgt_bf[((b * 25 + kk) * 128 + oh) * 128 + ow2] = f2bf(v[kk] * inv);
}

// ---------------------------------------------------------------------------
// K3: out[b][c][oh][ow] = sum_ij x[b][c][h+i-2][w+j-2] * wgt[b][ij][oh][ow]
// Block per (b,h): 512 blocks; computes BOTH oh rows (2h, 2h+1) sharing one
// x window. Thread = (w, c-group of 8); 4 outputs (2oh x 2ow) x 8c in regs.
// ---------------------------------------------------------------------------
__global__ __launch_bounds__(256) void k_reassemble(
    const float* __restrict__ x, const unsigned short* __restrict__ wgt_bf,
    float* __restrict__ out) {
  __shared__ unsigned short wgt_s[2][25][128];          // bf16, 12.8KB
  __shared__ __align__(16) float x_s[32][5][68];        // 43.5KB
  const int b = blockIdx.x >> 6;
  const int h = blockIdx.x & 63;
  const int t = threadIdx.x;

  for (int idx = t; idx < 2 * 25 * 128; idx += 256) {
    int ow = idx & 127;
    int kk = (idx >> 7) % 25;
    int r = idx / 3200;
    wgt_s[r][kk][ow] = wgt_bf[((b * 25 + kk) * 128 + 2 * h + r) * 128 + ow];
  }

  const int w = t & 63;
  const int g = t >> 6;

  for (int cc0 = 0; cc0 < 128; cc0 += 32) {
    __syncthreads();  // protects wgt_s (1st iter) + prior x_s reads
    for (int idx = t; idx < 32 * 5 * 68; idx += 256) {
      int cl = idx / 340;
      int rem = idx - cl * 340;
      int r = rem / 68;
      int wi = rem - r * 68;
      int hh = h + r - 2;
      int ww = wi - 2;
      x_s[cl][r][wi] = (hh >= 0 && hh < 64 && ww >= 0 && ww < 64)
                           ? x[((b * 128 + cc0 + cl) * 64 + hh) * 64 + ww]
                           : 0.f;
    }
    __syncthreads();

    float a00[8], a01[8], a10[8], a11[8];
#pragma unroll
    for (int k = 0; k < 8; ++k) { a00[k] = 0.f; a01[k] = 0.f; a10[k] = 0.f; a11[k] = 0.f; }

#pragma unroll
    for (int i = 0; i < 5; ++i)
#pragma unroll
      for (int j = 0; j < 5; ++j) {
        const int ij = i * 5 + j;
        float w00 = bf2f(wgt_s[0][ij][2 * w]);
        float w01 = bf2f(wgt_s[0][ij][2 * w + 1]);
        float w10 = bf2f(wgt_s[1][ij][2 * w]);
        float w11 = bf2f(wgt_s[1][ij][2 * w + 1]);
#pragma unroll
        for (int k = 0; k < 8; ++k) {
          float xv = x_s[g * 8 + k][i][w + j];
          a00[k] += xv * w00;
          a01[k] += xv * w01;
          a10[k] += xv * w10;
          a11[k] += xv * w11;
        }
      }

#pragma unroll
    for (int k = 0; k < 8; ++k) {
      int c = cc0 + g * 8 + k;
      *(float2*)&out[(size_t)(((b * 128 + c) * 128) + 2 * h) * 128 + 2 * w] =
          make_float2(a00[k], a01[k]);
      *(float2*)&out[(size_t)(((b * 128 + c) * 128) + 2 * h + 1) * 128 + 2 * w] =
          make_float2(a10[k], a11[k]);
    }
  }
}

// ---------------------------------------------------------------------------
extern "C" void kernel_launch(void* const* d_in, const int* in_sizes, int n_in,
                              void* d_out, int out_size, void* d_ws, size_t ws_size,
                              hipStream_t stream) {
  (void)in_sizes; (void)n_in; (void)out_size; (void)ws_size;
  const float* x  = (const float*)d_in[0];
  const float* cw = (const float*)d_in[1];
  const float* cb = (const float*)d_in[2];
  const float* ew = (const float*)d_in[3];
  const float* eb = (const float*)d_in[4];
  float* out = (float*)d_out;

  unsigned short* ws_u   = (unsigned short*)d_ws;
  unsigned short* m_t    = ws_u;                      // 2,097,152 ushorts (4 MiB)
  unsigned short* a_prep = ws_u + 2097152;            //    73,728 ushorts
  unsigned short* wgt_bf = ws_u + 2097152 + 73728;    // 3,276,800 ushorts (6.5 MiB)

  k_prep<<<dim3(288), dim3(256), 0, stream>>>(ew, a_prep);
  k_compress<<<dim3(512), dim3(256), 0, stream>>>(x, cw, cb, m_t);
  k_encoder_softmax<<<dim3(512), dim3(256), 0, stream>>>(m_t, a_prep, eb, wgt_bf);
  k_reassemble<<<dim3(512), dim3(256), 0, stream>>>(x, wgt_bf, out);
}

// Round 5
// 157.255 us; speedup vs baseline: 2.9671x; 1.2372x over previous
//
#include <hip/hip_runtime.h>
#include <math.h>

// CARAFE upsample: B=8, C=128, H=W=64, S=2, K=5, M=64, n_enc=100 (pad 128)
// K0 prep:      ew -> a_prep[9][128][64] bf16 ; cw -> cwT[c][mo] fp32
// K0b pad:      x -> xpad[b][c][68][72] bf16 (zero border of 2)
// K1 compress:  x -> m_t[b][h][w][mo] bf16 (SGPR weights, register acc)
// K2 encoder:   bf16 MFMA implicit GEMM + bias + pixelshuffle + softmax -> wgt_bf
// K3 reassemble: x from registers (via xpad), wgt in LDS, pk-fma, float4 stores.

typedef __attribute__((ext_vector_type(8))) short short8;
typedef __attribute__((ext_vector_type(4))) float floatx4;
typedef __attribute__((ext_vector_type(2))) float v2f;

__device__ __forceinline__ unsigned short f2bf(float f) {
  union { float f; unsigned int u; } v; v.f = f;
  unsigned int u = v.u + 0x7fffu + ((v.u >> 16) & 1u);  // RNE
  return (unsigned short)(u >> 16);
}
__device__ __forceinline__ void unpack2(unsigned int u, float& lo, float& hi) {
  union { unsigned int u; float f; } a, b;
  a.u = u << 16; b.u = u & 0xffff0000u;
  lo = a.f; hi = b.f;
}
__device__ __forceinline__ v2f unpack2v(unsigned int u) {
  union { unsigned int u; float f; } a, b;
  a.u = u << 16; b.u = u & 0xffff0000u;
  return (v2f){a.f, b.f};
}

// ---------------------------------------------------------------------------
// K0: a_prep[tap][n][mo] = bf16(ew[n][mo][tap]); cwT[c][mo] = cw[mo][c]
// ---------------------------------------------------------------------------
__global__ __launch_bounds__(256) void k_prep(const float* __restrict__ ew,
                                              const float* __restrict__ cw,
                                              unsigned short* __restrict__ a_prep,
                                              float* __restrict__ cwT) {
  int idx = blockIdx.x * 256 + threadIdx.x;
  if (idx < 9 * 128 * 64) {
    int mo = idx & 63;
    int n = (idx >> 6) & 127;
    int tap = idx >> 13;
    float v = (n < 100) ? ew[(n * 64 + mo) * 9 + tap] : 0.f;
    a_prep[idx] = f2bf(v);
  } else if (idx < 9 * 128 * 64 + 8192) {
    int r = idx - 9 * 128 * 64;
    int c = r >> 6, mo = r & 63;
    cwT[c * 64 + mo] = cw[mo * 128 + c];
  }
}

// ---------------------------------------------------------------------------
// K0b: xpad[b][c][hp][wp] = bf16(x[b][c][hp-2][wp-2]) or 0.  [68 rows][72 cols]
// Block per (b,c): 1024 blocks. ushort4 chunks, float4 fast path interior.
// ---------------------------------------------------------------------------
__global__ __launch_bounds__(256) void k_pad(const float* __restrict__ x,
                                             unsigned short* __restrict__ xpad) {
  const int bc = blockIdx.x;
  const float* xs = x + (size_t)bc * 4096;
  unsigned short* xd = xpad + (size_t)bc * 4896;
  for (int idx = threadIdx.x; idx < 1224; idx += 256) {  // 4896/4 ushort4 chunks
    int hp = idx / 18;                  // 18 chunks per 72-col row
    int q = idx - hp * 18;
    int hh = hp - 2;
    int w0 = q * 4 - 2;
    float v0, v1, v2, v3;
    if (hh >= 0 && hh < 64 && w0 >= 0 && w0 + 3 < 64) {
      float4 xv = *(const float4*)&xs[hh * 64 + w0];  // 4B-aligned, global OK
      v0 = xv.x; v1 = xv.y; v2 = xv.z; v3 = xv.w;
    } else {
      int base = hh * 64;
      bool hok = (hh >= 0 && hh < 64);
      v0 = (hok && w0 + 0 >= 0 && w0 + 0 < 64) ? xs[base + w0 + 0] : 0.f;
      v1 = (hok && w0 + 1 >= 0 && w0 + 1 < 64) ? xs[base + w0 + 1] : 0.f;
      v2 = (hok && w0 + 2 >= 0 && w0 + 2 < 64) ? xs[base + w0 + 2] : 0.f;
      v3 = (hok && w0 + 3 >= 0 && w0 + 3 < 64) ? xs[base + w0 + 3] : 0.f;
    }
    ushort4 o;
    o.x = f2bf(v0); o.y = f2bf(v1); o.z = f2bf(v2); o.w = f2bf(v3);
    *(ushort4*)&xd[idx * 4] = o;
  }
}

// ---------------------------------------------------------------------------
// K1: m_t[b][h][w][mo] = bf16( sum_c x[b][c][h][w]*cw[mo][c] + cb[mo] )
// Block (b,h): 512 blocks x 256 thr. lane = pixel w (coalesced x loads),
// wave wv owns mo [16wv,16wv+16): weights via wave-uniform scalar loads from
// cwT. 16 indep fmac chains/thread. Epilogue: 9KB LDS transpose -> b128 stores
// (two reps: 512 uint4 chunks cover all 64 w rows — R4 bugfix).
// ---------------------------------------------------------------------------
__global__ __launch_bounds__(256) void k_compress(
    const float* __restrict__ x, const float* __restrict__ cwT,
    const float* __restrict__ cb, unsigned short* __restrict__ m_t) {
  __shared__ __align__(16) unsigned short ms[64][72];  // [w][mo pad72] 9.2KB
  const int b = blockIdx.x >> 6;
  const int h = blockIdx.x & 63;
  const int wv = __builtin_amdgcn_readfirstlane((int)(threadIdx.x >> 6));
  const int lane = (int)(threadIdx.x & 63);
  const int mo0 = wv * 16;

  float acc[16];
#pragma unroll
  for (int k = 0; k < 16; ++k) acc[k] = 0.f;

  const float* xp = x + (((size_t)b * 128) * 64 + h) * 64 + lane;
  const float* wp = cwT + mo0;  // wave-uniform

#pragma unroll 4
  for (int c = 0; c < 128; ++c) {
    float xv = xp[(size_t)c * 4096];
#pragma unroll
    for (int k = 0; k < 16; ++k)
      acc[k] = fmaf(xv, wp[c * 64 + k], acc[k]);
  }

#pragma unroll
  for (int k = 0; k < 16; ++k) acc[k] += cb[mo0 + k];

#pragma unroll
  for (int k = 0; k < 8; ++k) {
    unsigned int p = ((unsigned int)f2bf(acc[2 * k + 1]) << 16) | f2bf(acc[2 * k]);
    *(unsigned int*)&ms[lane][mo0 + 2 * k] = p;
  }
  __syncthreads();
  const int t = threadIdx.x;
#pragma unroll
  for (int rep = 0; rep < 2; ++rep) {
    int idx = t + rep * 256;  // 0..511 -> w = idx>>3 in [0,64)
    uint4 v = *(const uint4*)&ms[idx >> 3][(idx & 7) * 8];
    *(uint4*)&m_t[(size_t)blockIdx.x * 4096 + idx * 8] = v;
  }
}

// ---------------------------------------------------------------------------
// K2: bf16 MFMA encoder conv + bias + pixelshuffle + softmax.
// ---------------------------------------------------------------------------
__global__ __launch_bounds__(256) void k_encoder_softmax(
    const unsigned short* __restrict__ m_t, const unsigned short* __restrict__ a_prep,
    const float* __restrict__ eb, unsigned short* __restrict__ wgt_bf) {
  __shared__ __align__(16) unsigned short m_s[3 * 64 * 72];  // [dh][w][mo pad 72]
  __shared__ __align__(16) float raw[128 * 66];              // [n][px pad 66]
  const int b = blockIdx.x >> 6;
  const int h = blockIdx.x & 63;
  const int t = threadIdx.x;

  for (int idx = t; idx < 3 * 64 * 8; idx += 256) {
    int r = idx >> 9;
    int rem = idx & 511;
    int w = rem >> 3, u = rem & 7;
    int hh = h + r - 1;
    uint4 val = make_uint4(0u, 0u, 0u, 0u);
    if (hh >= 0 && hh < 64)
      val = *(const uint4*)&m_t[(((b * 64 + hh) * 64 + w) * 64) + u * 8];
    *(uint4*)&m_s[(r * 64 + w) * 72 + u * 8] = val;
  }
  __syncthreads();

  const int wave = t >> 6, lane = t & 63;
  const int quad = lane >> 4, col = lane & 15;
  const int nbase = wave * 32;

  const floatx4 z4 = {0.f, 0.f, 0.f, 0.f};
  floatx4 acc[2][4];
#pragma unroll
  for (int i = 0; i < 2; ++i)
#pragma unroll
    for (int p = 0; p < 4; ++p) acc[i][p] = z4;

  const short8 z8 = {0, 0, 0, 0, 0, 0, 0, 0};

#pragma unroll
  for (int tap = 0; tap < 9; ++tap) {
    const int dh = tap / 3, dw = tap % 3;
#pragma unroll
    for (int half = 0; half < 2; ++half) {
      const int mo0 = half * 32;
      short8 a0 = *(const short8*)&a_prep[((tap * 128 + nbase + col) * 64) + mo0 + quad * 8];
      short8 a1 = *(const short8*)&a_prep[((tap * 128 + nbase + 16 + col) * 64) + mo0 + quad * 8];
#pragma unroll
      for (int p = 0; p < 4; ++p) {
        int wsrc = p * 16 + col + dw - 1;
        int wc = min(max(wsrc, 0), 63);
        short8 bf = *(const short8*)&m_s[(dh * 64 + wc) * 72 + mo0 + quad * 8];
        if (wsrc < 0 || wsrc > 63) bf = z8;
        acc[0][p] = __builtin_amdgcn_mfma_f32_16x16x32_bf16(a0, bf, acc[0][p], 0, 0, 0);
        acc[1][p] = __builtin_amdgcn_mfma_f32_16x16x32_bf16(a1, bf, acc[1][p], 0, 0, 0);
      }
    }
  }

#pragma unroll
  for (int i = 0; i < 2; ++i)
#pragma unroll
    for (int p = 0; p < 4; ++p)
#pragma unroll
      for (int r = 0; r < 4; ++r)
        raw[(nbase + i * 16 + quad * 4 + r) * 66 + p * 16 + col] = acc[i][p][r];
  __syncthreads();

  const int q = wave;
  float v[25];
  float mx = -1e30f;
#pragma unroll
  for (int kk = 0; kk < 25; ++kk) {
    v[kk] = raw[(kk * 4 + q) * 66 + lane] + eb[kk * 4 + q];
    mx = fmaxf(mx, v[kk]);
  }
  float s = 0.f;
#pragma unroll
  for (int kk = 0; kk < 25; ++kk) {
    v[kk] = __expf(v[kk] - mx);
    s += v[kk];
  }
  float inv = 1.f / s;
  const int oh = 2 * h + (q >> 1);
  const int ow2 = 2 * lane + (q & 1);
#pragma unroll
  for (int kk = 0; kk < 25; ++kk)
    wgt_bf[((b * 25 + kk) * 128 + oh) * 128 + ow2] = f2bf(v[kk] * inv);
}

// ---------------------------------------------------------------------------
// K3: out[b][c][oh][ow] = sum_ij xpad[b][c][h+i][w+j] * wgt[b][ij][oh][ow]
// Grid 1024 = (b,h,chalf). 256 thr = 16 wg(4 w each) x 16 cg(4 ch each).
// x: 1 global dwordx4 per (ch,row) from zero-padded bf16 xpad -> registers,
// no boundary logic. Weights: 12.8KB LDS, 1 b128 per (tap,oh). pk-fma over
// ow-pairs. acc 64 fp32; __launch_bounds__(256,4) caps VGPR at 128.
// ---------------------------------------------------------------------------
__global__ __launch_bounds__(256, 4) void k_reassemble(
    const unsigned short* __restrict__ xpad,
    const unsigned short* __restrict__ wgt_bf, float* __restrict__ out) {
  __shared__ __align__(16) unsigned short wgt_s[2][25][128];  // 12.8KB
  const int bh = blockIdx.x >> 1;
  const int chalf = blockIdx.x & 1;
  const int b = bh >> 6;
  const int h = bh & 63;
  const int t = threadIdx.x;

  // stage 50 weight rows (2 oh x 25 taps x 128 ow bf16) as 800 uint4 chunks
  for (int idx = t; idx < 800; idx += 256) {
    int r = (idx >= 400) ? 1 : 0;
    int rem = idx - r * 400;
    int kk = rem >> 4, ck = rem & 15;
    *(uint4*)&wgt_s[r][kk][ck * 8] =
        *(const uint4*)&wgt_bf[(((b * 25 + kk) * 128 + 2 * h + r) * 128) + ck * 8];
  }
  __syncthreads();

  const int wg = t & 15;        // fast index -> coalesced stores
  const int cg = t >> 4;
  const int w0 = wg * 4;
  const int c0 = chalf * 64 + cg * 4;

  const unsigned short* xb =
      xpad + ((size_t)(b * 128 + c0) * 4896) + h * 72 + w0;  // row h+i, col w0+..

  v2f acc[2][4][4];  // [oh][ch][k]; pair = (ow 2(w0+k), 2(w0+k)+1)
#pragma unroll
  for (int oh = 0; oh < 2; ++oh)
#pragma unroll
    for (int ch = 0; ch < 4; ++ch)
#pragma unroll
      for (int k = 0; k < 4; ++k) acc[oh][ch][k] = (v2f){0.f, 0.f};

  for (int i = 0; i < 5; ++i) {
    float xr[4][8];
#pragma unroll
    for (int ch = 0; ch < 4; ++ch) {
      uint4 rawv = *(const uint4*)(xb + ch * 4896 + i * 72);  // 8B-aligned, global OK
      unpack2(rawv.x, xr[ch][0], xr[ch][1]);
      unpack2(rawv.y, xr[ch][2], xr[ch][3]);
      unpack2(rawv.z, xr[ch][4], xr[ch][5]);
      unpack2(rawv.w, xr[ch][6], xr[ch][7]);
    }
#pragma unroll
    for (int j = 0; j < 5; ++j) {
      const int ij = i * 5 + j;
#pragma unroll
      for (int oh = 0; oh < 2; ++oh) {
        uint4 wr = *(const uint4*)&wgt_s[oh][ij][w0 * 2];  // 8 bf16 = this thread's 8 ow
        v2f wp[4];
        wp[0] = unpack2v(wr.x);
        wp[1] = unpack2v(wr.y);
        wp[2] = unpack2v(wr.z);
        wp[3] = unpack2v(wr.w);
#pragma unroll
        for (int k = 0; k < 4; ++k)
#pragma unroll
          for (int ch = 0; ch < 4; ++ch) {
            float xv = xr[ch][k + j];
            v2f xvv = {xv, xv};
            acc[oh][ch][k] += xvv * wp[k];  // v_pk_fma_f32
          }
      }
    }
  }

#pragma unroll
  for (int ch = 0; ch < 4; ++ch)
#pragma unroll
    for (int oh = 0; oh < 2; ++oh) {
      float* orow = out + ((size_t)(b * 128 + c0 + ch) * 128 + (2 * h + oh)) * 128 + w0 * 2;
      float4 f0 = make_float4(acc[oh][ch][0].x, acc[oh][ch][0].y,
                              acc[oh][ch][1].x, acc[oh][ch][1].y);
      float4 f1 = make_float4(acc[oh][ch][2].x, acc[oh][ch][2].y,
                              acc[oh][ch][3].x, acc[oh][ch][3].y);
      *(float4*)orow = f0;
      *(float4*)(orow + 4) = f1;
    }
}

// ---------------------------------------------------------------------------
extern "C" void kernel_launch(void* const* d_in, const int* in_sizes, int n_in,
                              void* d_out, int out_size, void* d_ws, size_t ws_size,
                              hipStream_t stream) {
  (void)in_sizes; (void)n_in; (void)out_size; (void)ws_size;
  const float* x  = (const float*)d_in[0];
  const float* cw = (const float*)d_in[1];
  const float* cb = (const float*)d_in[2];
  const float* ew = (const float*)d_in[3];
  const float* eb = (const float*)d_in[4];
  float* out = (float*)d_out;

  char* wsb = (char*)d_ws;
  unsigned short* m_t    = (unsigned short*)(wsb);                 // 4,194,304 B
  unsigned short* a_prep = (unsigned short*)(wsb + 4194304);       //   147,456 B
  unsigned short* wgt_bf = (unsigned short*)(wsb + 4341760);       // 6,553,600 B
  unsigned short* xpad   = (unsigned short*)(wsb + 10895360);      // 10,027,008 B
  float*          cwT    = (float*)(wsb + 20922368);               //    32,768 B

  k_prep<<<dim3(320), dim3(256), 0, stream>>>(ew, cw, a_prep, cwT);
  k_pad<<<dim3(1024), dim3(256), 0, stream>>>(x, xpad);
  k_compress<<<dim3(512), dim3(256), 0, stream>>>(x, cwT, cb, m_t);
  k_encoder_softmax<<<dim3(512), dim3(256), 0, stream>>>(m_t, a_prep, eb, wgt_bf);
  k_reassemble<<<dim3(1024), dim3(256), 0, stream>>>(xpad, wgt_bf, out);
}

// Round 6
// 156.687 us; speedup vs baseline: 2.9778x; 1.0036x over previous
//
#include <hip/hip_runtime.h>
#include <math.h>

// CARAFE upsample: B=8, C=128, H=W=64, S=2, K=5, M=64, n_enc=100 (pad 128)
// NOTE: ~97us of dur_us is harness re-poison fills (256MiB ws + 64MiB out)
// inside the timed window — our 4 kernels sum to ~60us (R5 post-mortem).
// K0 prep+pad:  ew->a_prep bf16, cw->cwT, x->xpad[b][c][68][72] bf16 (one dispatch)
// K1 compress:  x -> m_t[b][h][w][mo] bf16 (SGPR weights, register acc)
// K2 encoder:   bf16 MFMA implicit GEMM + pixelshuffle + softmax -> wgt_bf
//               (m_s/raw LDS union: 33.8KB -> 4 blocks/CU, was 61KB/2)
// K3 reassemble: x regs via xpad, wgt LDS, pk-fma, float4 stores.

typedef __attribute__((ext_vector_type(8))) short short8;
typedef __attribute__((ext_vector_type(4))) float floatx4;
typedef __attribute__((ext_vector_type(2))) float v2f;

__device__ __forceinline__ unsigned short f2bf(float f) {
  union { float f; unsigned int u; } v; v.f = f;
  unsigned int u = v.u + 0x7fffu + ((v.u >> 16) & 1u);  // RNE
  return (unsigned short)(u >> 16);
}
__device__ __forceinline__ void unpack2(unsigned int u, float& lo, float& hi) {
  union { unsigned int u; float f; } a, b;
  a.u = u << 16; b.u = u & 0xffff0000u;
  lo = a.f; hi = b.f;
}
__device__ __forceinline__ v2f unpack2v(unsigned int u) {
  union { unsigned int u; float f; } a, b;
  a.u = u << 16; b.u = u & 0xffff0000u;
  return (v2f){a.f, b.f};
}

// ---------------------------------------------------------------------------
// K0: blocks [0,1024): xpad[b][c][hp][wp] = bf16(x[..]) zero-bordered.
//     blocks [1024,1344): a_prep[tap][n][mo] = bf16(ew[n][mo][tap]) (n>=100 ->0)
//                         cwT[c][mo] = cw[mo][c]
// ---------------------------------------------------------------------------
__global__ __launch_bounds__(256) void k_prep_pad(
    const float* __restrict__ x, const float* __restrict__ ew,
    const float* __restrict__ cw, unsigned short* __restrict__ a_prep,
    float* __restrict__ cwT, unsigned short* __restrict__ xpad) {
  const int blk = blockIdx.x;
  if (blk < 1024) {
    const float* xs = x + (size_t)blk * 4096;
    unsigned short* xd = xpad + (size_t)blk * 4896;
    for (int idx = threadIdx.x; idx < 1224; idx += 256) {  // ushort4 chunks
      int hp = idx / 18;
      int q = idx - hp * 18;
      int hh = hp - 2;
      int w0 = q * 4 - 2;
      float v0, v1, v2, v3;
      if (hh >= 0 && hh < 64 && w0 >= 0 && w0 + 3 < 64) {
        float4 xv = *(const float4*)&xs[hh * 64 + w0];
        v0 = xv.x; v1 = xv.y; v2 = xv.z; v3 = xv.w;
      } else {
        int base = hh * 64;
        bool hok = (hh >= 0 && hh < 64);
        v0 = (hok && w0 + 0 >= 0 && w0 + 0 < 64) ? xs[base + w0 + 0] : 0.f;
        v1 = (hok && w0 + 1 >= 0 && w0 + 1 < 64) ? xs[base + w0 + 1] : 0.f;
        v2 = (hok && w0 + 2 >= 0 && w0 + 2 < 64) ? xs[base + w0 + 2] : 0.f;
        v3 = (hok && w0 + 3 >= 0 && w0 + 3 < 64) ? xs[base + w0 + 3] : 0.f;
      }
      ushort4 o;
      o.x = f2bf(v0); o.y = f2bf(v1); o.z = f2bf(v2); o.w = f2bf(v3);
      *(ushort4*)&xd[idx * 4] = o;
    }
  } else {
    int idx = (blk - 1024) * 256 + (int)threadIdx.x;  // [0, 81920)
    if (idx < 9 * 128 * 64) {
      int mo = idx & 63;
      int n = (idx >> 6) & 127;
      int tap = idx >> 13;
      float v = (n < 100) ? ew[(n * 64 + mo) * 9 + tap] : 0.f;
      a_prep[idx] = f2bf(v);
    } else {
      int r = idx - 9 * 128 * 64;  // [0, 8192)
      int c = r >> 6, mo = r & 63;
      cwT[c * 64 + mo] = cw[mo * 128 + c];
    }
  }
}

// ---------------------------------------------------------------------------
// K1: m_t[b][h][w][mo] = bf16( sum_c x[b][c][h][w]*cw[mo][c] + cb[mo] )
// Block (b,h): 512 blocks x 256 thr. lane = pixel w (coalesced x loads),
// wave wv owns mo [16wv,16wv+16): weights via wave-uniform scalar loads.
// Epilogue: 9KB LDS transpose -> 512 uint4 b128 stores (covers all 64 w).
// ---------------------------------------------------------------------------
__global__ __launch_bounds__(256) void k_compress(
    const float* __restrict__ x, const float* __restrict__ cwT,
    const float* __restrict__ cb, unsigned short* __restrict__ m_t) {
  __shared__ __align__(16) unsigned short ms[64][72];  // 9.2KB
  const int b = blockIdx.x >> 6;
  const int h = blockIdx.x & 63;
  const int wv = __builtin_amdgcn_readfirstlane((int)(threadIdx.x >> 6));
  const int lane = (int)(threadIdx.x & 63);
  const int mo0 = wv * 16;

  float acc[16];
#pragma unroll
  for (int k = 0; k < 16; ++k) acc[k] = 0.f;

  const float* xp = x + (((size_t)b * 128) * 64 + h) * 64 + lane;
  const float* wp = cwT + mo0;  // wave-uniform

#pragma unroll 4
  for (int c = 0; c < 128; ++c) {
    float xv = xp[(size_t)c * 4096];
#pragma unroll
    for (int k = 0; k < 16; ++k)
      acc[k] = fmaf(xv, wp[c * 64 + k], acc[k]);
  }

#pragma unroll
  for (int k = 0; k < 16; ++k) acc[k] += cb[mo0 + k];

#pragma unroll
  for (int k = 0; k < 8; ++k) {
    unsigned int p = ((unsigned int)f2bf(acc[2 * k + 1]) << 16) | f2bf(acc[2 * k]);
    *(unsigned int*)&ms[lane][mo0 + 2 * k] = p;
  }
  __syncthreads();
  const int t = threadIdx.x;
#pragma unroll
  for (int rep = 0; rep < 2; ++rep) {
    int idx = t + rep * 256;  // 0..511 -> w = idx>>3 in [0,64)
    uint4 v = *(const uint4*)&ms[idx >> 3][(idx & 7) * 8];
    *(uint4*)&m_t[(size_t)blockIdx.x * 4096 + idx * 8] = v;
  }
}

// ---------------------------------------------------------------------------
// K2: bf16 MFMA encoder conv + bias + pixelshuffle + softmax.
// LDS UNION: m_s (27.6KB, input tiles) and raw (33.8KB, output transpose)
// share one 33.8KB block -> 4 blocks/CU (was 61KB -> 2). m_s is dead after
// the MFMA loop; barrier before raw writes.
// ---------------------------------------------------------------------------
__global__ __launch_bounds__(256) void k_encoder_softmax(
    const unsigned short* __restrict__ m_t, const unsigned short* __restrict__ a_prep,
    const float* __restrict__ eb, unsigned short* __restrict__ wgt_bf) {
  __shared__ __align__(16) float raw[128 * 66];        // 33.8KB, unioned
  unsigned short* m_s = (unsigned short*)raw;          // [dh][w][mo pad72] 27.6KB
  const int b = blockIdx.x >> 6;
  const int h = blockIdx.x & 63;
  const int t = threadIdx.x;

  for (int idx = t; idx < 3 * 64 * 8; idx += 256) {
    int r = idx >> 9;
    int rem = idx & 511;
    int w = rem >> 3, u = rem & 7;
    int hh = h + r - 1;
    uint4 val = make_uint4(0u, 0u, 0u, 0u);
    if (hh >= 0 && hh < 64)
      val = *(const uint4*)&m_t[(((b * 64 + hh) * 64 + w) * 64) + u * 8];
    *(uint4*)&m_s[(r * 64 + w) * 72 + u * 8] = val;
  }
  __syncthreads();

  const int wave = t >> 6, lane = t & 63;
  const int quad = lane >> 4, col = lane & 15;
  const int nbase = wave * 32;

  const floatx4 z4 = {0.f, 0.f, 0.f, 0.f};
  floatx4 acc[2][4];
#pragma unroll
  for (int i = 0; i < 2; ++i)
#pragma unroll
    for (int p = 0; p < 4; ++p) acc[i][p] = z4;

  const short8 z8 = {0, 0, 0, 0, 0, 0, 0, 0};

#pragma unroll
  for (int tap = 0; tap < 9; ++tap) {
    const int dh = tap / 3, dw = tap % 3;
#pragma unroll
    for (int half = 0; half < 2; ++half) {
      const int mo0 = half * 32;
      short8 a0 = *(const short8*)&a_prep[((tap * 128 + nbase + col) * 64) + mo0 + quad * 8];
      short8 a1 = *(const short8*)&a_prep[((tap * 128 + nbase + 16 + col) * 64) + mo0 + quad * 8];
#pragma unroll
      for (int p = 0; p < 4; ++p) {
        int wsrc = p * 16 + col + dw - 1;
        int wc = min(max(wsrc, 0), 63);
        short8 bf = *(const short8*)&m_s[(dh * 64 + wc) * 72 + mo0 + quad * 8];
        if (wsrc < 0 || wsrc > 63) bf = z8;
        acc[0][p] = __builtin_amdgcn_mfma_f32_16x16x32_bf16(a0, bf, acc[0][p], 0, 0, 0);
        acc[1][p] = __builtin_amdgcn_mfma_f32_16x16x32_bf16(a1, bf, acc[1][p], 0, 0, 0);
      }
    }
  }

  __syncthreads();  // all m_s reads done before raw overwrites the union
#pragma unroll
  for (int i = 0; i < 2; ++i)
#pragma unroll
    for (int p = 0; p < 4; ++p)
#pragma unroll
      for (int r = 0; r < 4; ++r)
        raw[(nbase + i * 16 + quad * 4 + r) * 66 + p * 16 + col] = acc[i][p][r];
  __syncthreads();

  const int q = wave;
  float v[25];
  float mx = -1e30f;
#pragma unroll
  for (int kk = 0; kk < 25; ++kk) {
    v[kk] = raw[(kk * 4 + q) * 66 + lane] + eb[kk * 4 + q];
    mx = fmaxf(mx, v[kk]);
  }
  float s = 0.f;
#pragma unroll
  for (int kk = 0; kk < 25; ++kk) {
    v[kk] = __expf(v[kk] - mx);
    s += v[kk];
  }
  float inv = 1.f / s;
  const int oh = 2 * h + (q >> 1);
  const int ow2 = 2 * lane + (q & 1);
#pragma unroll
  for (int kk = 0; kk < 25; ++kk)
    wgt_bf[((b * 25 + kk) * 128 + oh) * 128 + ow2] = f2bf(v[kk] * inv);
}

// ---------------------------------------------------------------------------
// K3: out[b][c][oh][ow] = sum_ij xpad[b][c][h+i][w+j] * wgt[b][ij][oh][ow]
// Grid 1024 = (b,h,chalf). 256 thr = 16 wg(4 w each) x 16 cg(4 ch each).
// x: 1 global dwordx4 per (ch,row) from zero-padded bf16 xpad -> registers.
// Weights: 12.8KB LDS. pk-fma over ow-pairs; float4 stores.
// ---------------------------------------------------------------------------
__global__ __launch_bounds__(256, 4) void k_reassemble(
    const unsigned short* __restrict__ xpad,
    const unsigned short* __restrict__ wgt_bf, float* __restrict__ out) {
  __shared__ __align__(16) unsigned short wgt_s[2][25][128];  // 12.8KB
  const int bh = blockIdx.x >> 1;
  const int chalf = blockIdx.x & 1;
  const int b = bh >> 6;
  const int h = bh & 63;
  const int t = threadIdx.x;

  for (int idx = t; idx < 800; idx += 256) {
    int r = (idx >= 400) ? 1 : 0;
    int rem = idx - r * 400;
    int kk = rem >> 4, ck = rem & 15;
    *(uint4*)&wgt_s[r][kk][ck * 8] =
        *(const uint4*)&wgt_bf[(((b * 25 + kk) * 128 + 2 * h + r) * 128) + ck * 8];
  }
  __syncthreads();

  const int wg = t & 15;
  const int cg = t >> 4;
  const int w0 = wg * 4;
  const int c0 = chalf * 64 + cg * 4;

  const unsigned short* xb =
      xpad + ((size_t)(b * 128 + c0) * 4896) + h * 72 + w0;

  v2f acc[2][4][4];  // [oh][ch][k]
#pragma unroll
  for (int oh = 0; oh < 2; ++oh)
#pragma unroll
    for (int ch = 0; ch < 4; ++ch)
#pragma unroll
      for (int k = 0; k < 4; ++k) acc[oh][ch][k] = (v2f){0.f, 0.f};

  for (int i = 0; i < 5; ++i) {
    float xr[4][8];
#pragma unroll
    for (int ch = 0; ch < 4; ++ch) {
      uint4 rawv = *(const uint4*)(xb + ch * 4896 + i * 72);
      unpack2(rawv.x, xr[ch][0], xr[ch][1]);
      unpack2(rawv.y, xr[ch][2], xr[ch][3]);
      unpack2(rawv.z, xr[ch][4], xr[ch][5]);
      unpack2(rawv.w, xr[ch][6], xr[ch][7]);
    }
#pragma unroll
    for (int j = 0; j < 5; ++j) {
      const int ij = i * 5 + j;
#pragma unroll
      for (int oh = 0; oh < 2; ++oh) {
        uint4 wr = *(const uint4*)&wgt_s[oh][ij][w0 * 2];
        v2f wp[4];
        wp[0] = unpack2v(wr.x);
        wp[1] = unpack2v(wr.y);
        wp[2] = unpack2v(wr.z);
        wp[3] = unpack2v(wr.w);
#pragma unroll
        for (int k = 0; k < 4; ++k)
#pragma unroll
          for (int ch = 0; ch < 4; ++ch) {
            float xv = xr[ch][k + j];
            v2f xvv = {xv, xv};
            acc[oh][ch][k] += xvv * wp[k];  // v_pk_fma_f32
          }
      }
    }
  }

#pragma unroll
  for (int ch = 0; ch < 4; ++ch)
#pragma unroll
    for (int oh = 0; oh < 2; ++oh) {
      float* orow = out + ((size_t)(b * 128 + c0 + ch) * 128 + (2 * h + oh)) * 128 + w0 * 2;
      float4 f0 = make_float4(acc[oh][ch][0].x, acc[oh][ch][0].y,
                              acc[oh][ch][1].x, acc[oh][ch][1].y);
      float4 f1 = make_float4(acc[oh][ch][2].x, acc[oh][ch][2].y,
                              acc[oh][ch][3].x, acc[oh][ch][3].y);
      *(float4*)orow = f0;
      *(float4*)(orow + 4) = f1;
    }
}

// ---------------------------------------------------------------------------
extern "C" void kernel_launch(void* const* d_in, const int* in_sizes, int n_in,
                              void* d_out, int out_size, void* d_ws, size_t ws_size,
                              hipStream_t stream) {
  (void)in_sizes; (void)n_in; (void)out_size; (void)ws_size;
  const float* x  = (const float*)d_in[0];
  const float* cw = (const float*)d_in[1];
  const float* cb = (const float*)d_in[2];
  const float* ew = (const float*)d_in[3];
  const float* eb = (const float*)d_in[4];
  float* out = (float*)d_out;

  char* wsb = (char*)d_ws;
  unsigned short* m_t    = (unsigned short*)(wsb);                 // 4,194,304 B
  unsigned short* a_prep = (unsigned short*)(wsb + 4194304);       //   147,456 B
  unsigned short* wgt_bf = (unsigned short*)(wsb + 4341760);       // 6,553,600 B
  unsigned short* xpad   = (unsigned short*)(wsb + 10895360);      // 10,027,008 B
  float*          cwT    = (float*)(wsb + 20922368);               //    32,768 B

  k_prep_pad<<<dim3(1344), dim3(256), 0, stream>>>(x, ew, cw, a_prep, cwT, xpad);
  k_compress<<<dim3(512), dim3(256), 0, stream>>>(x, cwT, cb, m_t);
  k_encoder_softmax<<<dim3(512), dim3(256), 0, stream>>>(m_t, a_prep, eb, wgt_bf);
  k_reassemble<<<dim3(1024), dim3(256), 0, stream>>>(xpad, wgt_bf, out);
}

// Round 7
// 145.388 us; speedup vs baseline: 3.2092x; 1.0777x over previous
//
#include <hip/hip_runtime.h>
#include <math.h>

// CARAFE upsample: B=8, C=128, H=W=64, S=2, K=5, M=64, n_enc=100 (pad 128)
// NOTE: ~55-65us of dur_us is harness re-poison fill (256MiB ws @ ~44us,
// HBM-bound) + input restore inside the timed window — fixed floor.
// 3 dispatches:
//  K0 prep+pad: ew->a_prep bf16, cw->cwT, x->xpad[b][c][68][72] bf16
//  K1 compress: x -> m_t[b][h][w][mo] bf16 (SGPR weights, register acc)
//  K2 main:     bf16 MFMA encoder conv + pixelshuffle + softmax -> LDS wgt
//               -> fused reassembly (25-tap weighted sum) -> out.
//               wgt never touches global memory (R7 fusion).

typedef __attribute__((ext_vector_type(8))) short short8;
typedef __attribute__((ext_vector_type(4))) float floatx4;
typedef __attribute__((ext_vector_type(2))) float v2f;

__device__ __forceinline__ unsigned short f2bf(float f) {
  union { float f; unsigned int u; } v; v.f = f;
  unsigned int u = v.u + 0x7fffu + ((v.u >> 16) & 1u);  // RNE
  return (unsigned short)(u >> 16);
}
__device__ __forceinline__ void unpack2(unsigned int u, float& lo, float& hi) {
  union { unsigned int u; float f; } a, b;
  a.u = u << 16; b.u = u & 0xffff0000u;
  lo = a.f; hi = b.f;
}
__device__ __forceinline__ v2f unpack2v(unsigned int u) {
  union { unsigned int u; float f; } a, b;
  a.u = u << 16; b.u = u & 0xffff0000u;
  return (v2f){a.f, b.f};
}

// ---------------------------------------------------------------------------
// K0: blocks [0,1024): xpad[b][c] = bf16(x) zero-bordered [68][72].
//     blocks [1024,1344): a_prep[tap][n][mo] = bf16(ew[n][mo][tap]) (n>=100->0)
//                         cwT[c][mo] = cw[mo][c]
// ---------------------------------------------------------------------------
__global__ __launch_bounds__(256) void k_prep_pad(
    const float* __restrict__ x, const float* __restrict__ ew,
    const float* __restrict__ cw, unsigned short* __restrict__ a_prep,
    float* __restrict__ cwT, unsigned short* __restrict__ xpad) {
  const int blk = blockIdx.x;
  if (blk < 1024) {
    const float* xs = x + (size_t)blk * 4096;
    unsigned short* xd = xpad + (size_t)blk * 4896;
    for (int idx = threadIdx.x; idx < 1224; idx += 256) {  // ushort4 chunks
      int hp = idx / 18;
      int q = idx - hp * 18;
      int hh = hp - 2;
      int w0 = q * 4 - 2;
      float v0, v1, v2, v3;
      if (hh >= 0 && hh < 64 && w0 >= 0 && w0 + 3 < 64) {
        float4 xv = *(const float4*)&xs[hh * 64 + w0];
        v0 = xv.x; v1 = xv.y; v2 = xv.z; v3 = xv.w;
      } else {
        int base = hh * 64;
        bool hok = (hh >= 0 && hh < 64);
        v0 = (hok && w0 + 0 >= 0 && w0 + 0 < 64) ? xs[base + w0 + 0] : 0.f;
        v1 = (hok && w0 + 1 >= 0 && w0 + 1 < 64) ? xs[base + w0 + 1] : 0.f;
        v2 = (hok && w0 + 2 >= 0 && w0 + 2 < 64) ? xs[base + w0 + 2] : 0.f;
        v3 = (hok && w0 + 3 >= 0 && w0 + 3 < 64) ? xs[base + w0 + 3] : 0.f;
      }
      ushort4 o;
      o.x = f2bf(v0); o.y = f2bf(v1); o.z = f2bf(v2); o.w = f2bf(v3);
      *(ushort4*)&xd[idx * 4] = o;
    }
  } else {
    int idx = (blk - 1024) * 256 + (int)threadIdx.x;  // [0, 81920)
    if (idx < 9 * 128 * 64) {
      int mo = idx & 63;
      int n = (idx >> 6) & 127;
      int tap = idx >> 13;
      float v = (n < 100) ? ew[(n * 64 + mo) * 9 + tap] : 0.f;
      a_prep[idx] = f2bf(v);
    } else {
      int r = idx - 9 * 128 * 64;  // [0, 8192)
      int c = r >> 6, mo = r & 63;
      cwT[c * 64 + mo] = cw[mo * 128 + c];
    }
  }
}

// ---------------------------------------------------------------------------
// K1: m_t[b][h][w][mo] = bf16( sum_c x[b][c][h][w]*cw[mo][c] + cb[mo] )
// Block (b,h): 512 blocks x 256 thr. lane = pixel w (coalesced x loads),
// wave wv owns mo [16wv,16wv+16): weights via wave-uniform scalar loads.
// Epilogue: 9KB LDS transpose -> 512 uint4 b128 stores.
// ---------------------------------------------------------------------------
__global__ __launch_bounds__(256) void k_compress(
    const float* __restrict__ x, const float* __restrict__ cwT,
    const float* __restrict__ cb, unsigned short* __restrict__ m_t) {
  __shared__ __align__(16) unsigned short ms[64][72];  // 9.2KB
  const int b = blockIdx.x >> 6;
  const int h = blockIdx.x & 63;
  const int wv = __builtin_amdgcn_readfirstlane((int)(threadIdx.x >> 6));
  const int lane = (int)(threadIdx.x & 63);
  const int mo0 = wv * 16;

  float acc[16];
#pragma unroll
  for (int k = 0; k < 16; ++k) acc[k] = 0.f;

  const float* xp = x + (((size_t)b * 128) * 64 + h) * 64 + lane;
  const float* wp = cwT + mo0;  // wave-uniform

#pragma unroll 4
  for (int c = 0; c < 128; ++c) {
    float xv = xp[(size_t)c * 4096];
#pragma unroll
    for (int k = 0; k < 16; ++k)
      acc[k] = fmaf(xv, wp[c * 64 + k], acc[k]);
  }

#pragma unroll
  for (int k = 0; k < 16; ++k) acc[k] += cb[mo0 + k];

#pragma unroll
  for (int k = 0; k < 8; ++k) {
    unsigned int p = ((unsigned int)f2bf(acc[2 * k + 1]) << 16) | f2bf(acc[2 * k]);
    *(unsigned int*)&ms[lane][mo0 + 2 * k] = p;
  }
  __syncthreads();
  const int t = threadIdx.x;
#pragma unroll
  for (int rep = 0; rep < 2; ++rep) {
    int idx = t + rep * 256;  // 0..511 -> w = idx>>3 in [0,64)
    uint4 v = *(const uint4*)&ms[idx >> 3][(idx & 7) * 8];
    *(uint4*)&m_t[(size_t)blockIdx.x * 4096 + idx * 8] = v;
  }
}

// ---------------------------------------------------------------------------
// K2 main (fused encoder+softmax+reassemble). Block per (b,h): 512 x 256.
// Phase A: bf16 MFMA 3x3 conv (64->128ch), pixelshuffle+softmax -> LDS wgt_s.
// Phase B: out[b][c][2h+oh][ow] = sum_ij xpad[b][c][h+i][w+j]*wgt_s[oh][ij][ow]
//          chalf loop: thread = (wg 16 x cg 16), 4ch x (4w x 2ow) x 2oh regs.
// LDS union: m_s (27.6KB) / raw (33.8KB) / wgt_s (12.8KB) share one region.
// ---------------------------------------------------------------------------
__global__ __launch_bounds__(256) void k_main(
    const unsigned short* __restrict__ m_t, const unsigned short* __restrict__ a_prep,
    const float* __restrict__ eb, const unsigned short* __restrict__ xpad,
    float* __restrict__ out) {
  __shared__ __align__(16) float raw[128 * 66];   // 33.8KB union
  unsigned short* m_s = (unsigned short*)raw;     // [dh][w][mo pad72] 27.6KB
  unsigned short* wgt_s = (unsigned short*)raw;   // [oh2][kk25][ow128] 12.8KB
  const int b = blockIdx.x >> 6;
  const int h = blockIdx.x & 63;
  const int t = threadIdx.x;

  // ---- Phase A: stage m rows h-1,h,h+1 ----
  for (int idx = t; idx < 3 * 64 * 8; idx += 256) {
    int r = idx >> 9;
    int rem = idx & 511;
    int w = rem >> 3, u = rem & 7;
    int hh = h + r - 1;
    uint4 val = make_uint4(0u, 0u, 0u, 0u);
    if (hh >= 0 && hh < 64)
      val = *(const uint4*)&m_t[(((b * 64 + hh) * 64 + w) * 64) + u * 8];
    *(uint4*)&m_s[(r * 64 + w) * 72 + u * 8] = val;
  }
  __syncthreads();

  const int wave = t >> 6, lane = t & 63;
  const int quad = lane >> 4, col = lane & 15;
  const int nbase = wave * 32;

  const floatx4 z4 = {0.f, 0.f, 0.f, 0.f};
  floatx4 acc[2][4];
#pragma unroll
  for (int i = 0; i < 2; ++i)
#pragma unroll
    for (int p = 0; p < 4; ++p) acc[i][p] = z4;

  const short8 z8 = {0, 0, 0, 0, 0, 0, 0, 0};

#pragma unroll
  for (int tap = 0; tap < 9; ++tap) {
    const int dh = tap / 3, dw = tap % 3;
#pragma unroll
    for (int half = 0; half < 2; ++half) {
      const int mo0 = half * 32;
      short8 a0 = *(const short8*)&a_prep[((tap * 128 + nbase + col) * 64) + mo0 + quad * 8];
      short8 a1 = *(const short8*)&a_prep[((tap * 128 + nbase + 16 + col) * 64) + mo0 + quad * 8];
#pragma unroll
      for (int p = 0; p < 4; ++p) {
        int wsrc = p * 16 + col + dw - 1;
        int wc = min(max(wsrc, 0), 63);
        short8 bf = *(const short8*)&m_s[(dh * 64 + wc) * 72 + mo0 + quad * 8];
        if (wsrc < 0 || wsrc > 63) bf = z8;
        acc[0][p] = __builtin_amdgcn_mfma_f32_16x16x32_bf16(a0, bf, acc[0][p], 0, 0, 0);
        acc[1][p] = __builtin_amdgcn_mfma_f32_16x16x32_bf16(a1, bf, acc[1][p], 0, 0, 0);
      }
    }
  }

  __syncthreads();  // m_s dead; raw takes over the union
#pragma unroll
  for (int i = 0; i < 2; ++i)
#pragma unroll
    for (int p = 0; p < 4; ++p)
#pragma unroll
      for (int r = 0; r < 4; ++r)
        raw[(nbase + i * 16 + quad * 4 + r) * 66 + p * 16 + col] = acc[i][p][r];
  __syncthreads();

  // softmax over kk (n = kk*4+q), q = wave, px = lane
  const int q = wave;
  float v[25];
  float mx = -1e30f;
#pragma unroll
  for (int kk = 0; kk < 25; ++kk) {
    v[kk] = raw[(kk * 4 + q) * 66 + lane] + eb[kk * 4 + q];
    mx = fmaxf(mx, v[kk]);
  }
  float s = 0.f;
#pragma unroll
  for (int kk = 0; kk < 25; ++kk) {
    v[kk] = __expf(v[kk] - mx);
    s += v[kk];
  }
  float inv = 1.f / s;

  __syncthreads();  // raw reads done; wgt_s takes over the union
  {
    const int ohl = q >> 1;
    const int owp = 2 * lane + (q & 1);
#pragma unroll
    for (int kk = 0; kk < 25; ++kk)
      wgt_s[(ohl * 25 + kk) * 128 + owp] = f2bf(v[kk] * inv);
  }
  __syncthreads();

  // ---- Phase B: reassembly, both channel halves ----
  const int wg = t & 15;
  const int cg = t >> 4;
  const int w0 = wg * 4;

  for (int chalf = 0; chalf < 2; ++chalf) {
    const int c0 = chalf * 64 + cg * 4;
    const unsigned short* xb =
        xpad + ((size_t)(b * 128 + c0) * 4896) + h * 72 + w0;

    v2f accB[2][4][4];  // [oh][ch][k]
#pragma unroll
    for (int oh = 0; oh < 2; ++oh)
#pragma unroll
      for (int ch = 0; ch < 4; ++ch)
#pragma unroll
        for (int k = 0; k < 4; ++k) accB[oh][ch][k] = (v2f){0.f, 0.f};

    for (int i = 0; i < 5; ++i) {
      float xr[4][8];
#pragma unroll
      for (int ch = 0; ch < 4; ++ch) {
        uint4 rawv = *(const uint4*)(xb + ch * 4896 + i * 72);
        unpack2(rawv.x, xr[ch][0], xr[ch][1]);
        unpack2(rawv.y, xr[ch][2], xr[ch][3]);
        unpack2(rawv.z, xr[ch][4], xr[ch][5]);
        unpack2(rawv.w, xr[ch][6], xr[ch][7]);
      }
#pragma unroll
      for (int j = 0; j < 5; ++j) {
        const int ij = i * 5 + j;
#pragma unroll
        for (int oh = 0; oh < 2; ++oh) {
          uint4 wr = *(const uint4*)&wgt_s[(oh * 25 + ij) * 128 + w0 * 2];
          v2f wp[4];
          wp[0] = unpack2v(wr.x);
          wp[1] = unpack2v(wr.y);
          wp[2] = unpack2v(wr.z);
          wp[3] = unpack2v(wr.w);
#pragma unroll
          for (int k = 0; k < 4; ++k)
#pragma unroll
            for (int ch = 0; ch < 4; ++ch) {
              float xv = xr[ch][k + j];
              v2f xvv = {xv, xv};
              accB[oh][ch][k] += xvv * wp[k];  // v_pk_fma_f32
            }
        }
      }
    }

#pragma unroll
    for (int ch = 0; ch < 4; ++ch)
#pragma unroll
      for (int oh = 0; oh < 2; ++oh) {
        float* orow =
            out + ((size_t)(b * 128 + c0 + ch) * 128 + (2 * h + oh)) * 128 + w0 * 2;
        float4 f0 = make_float4(accB[oh][ch][0].x, accB[oh][ch][0].y,
                                accB[oh][ch][1].x, accB[oh][ch][1].y);
        float4 f1 = make_float4(accB[oh][ch][2].x, accB[oh][ch][2].y,
                                accB[oh][ch][3].x, accB[oh][ch][3].y);
        *(float4*)orow = f0;
        *(float4*)(orow + 4) = f1;
      }
  }
}

// ---------------------------------------------------------------------------
extern "C" void kernel_launch(void* const* d_in, const int* in_sizes, int n_in,
                              void* d_out, int out_size, void* d_ws, size_t ws_size,
                              hipStream_t stream) {
  (void)in_sizes; (void)n_in; (void)out_size; (void)ws_size;
  const float* x  = (const float*)d_in[0];
  const float* cw = (const float*)d_in[1];
  const float* cb = (const float*)d_in[2];
  const float* ew = (const float*)d_in[3];
  const float* eb = (const float*)d_in[4];
  float* out = (float*)d_out;

  char* wsb = (char*)d_ws;
  unsigned short* m_t    = (unsigned short*)(wsb);               // 4,194,304 B
  unsigned short* a_prep = (unsigned short*)(wsb + 4194304);     //   147,456 B
  unsigned short* xpad   = (unsigned short*)(wsb + 4341760);     // 10,027,008 B
  float*          cwT    = (float*)(wsb + 14368768);             //    32,768 B

  k_prep_pad<<<dim3(1344), dim3(256), 0, stream>>>(x, ew, cw, a_prep, cwT, xpad);
  k_compress<<<dim3(512), dim3(256), 0, stream>>>(x, cwT, cb, m_t);
  k_main<<<dim3(512), dim3(256), 0, stream>>>(m_t, a_prep, eb, xpad, out);
}